// Round 12
// baseline (414.256 us; speedup 1.0000x reference)
//
#include <hip/hip_runtime.h>
#include <stdint.h>

// ---- problem dims (fixed) ----
// B=4, T=S=2048, C=1024, H=16, D=64
#define NB 4
#define NT 2048
#define NC 1024
#define NH 16
#define ND 64
#define ACT_ELEMS (8388608ull)   /* B*T*C = 8M */
#define W_ELEMS   (1048576ull)   /* C*C = 1M  */

typedef __attribute__((ext_vector_type(8))) short short8;
typedef __attribute__((ext_vector_type(4))) float f32x4;
typedef __attribute__((ext_vector_type(2))) unsigned int u32x2;

__device__ __forceinline__ unsigned short f2bf(float x) {
    unsigned int u = __float_as_uint(x);
    u += 0x7fffu + ((u >> 16) & 1u);   // RNE
    return (unsigned short)(u >> 16);
}

// hardware packed f32->bf16 (RNE), 1 VALU op for 2 values [T12 primitive]
__device__ __forceinline__ unsigned int cvtpk_bf16(float a, float b) {
    unsigned int r;
    asm("v_cvt_pk_bf16_f32 %0, %1, %2" : "=v"(r) : "v"(a), "v"(b));
    return r;
}

__device__ __forceinline__ float fexp2(float x) {
#if defined(__has_builtin) && __has_builtin(__builtin_amdgcn_exp2f)
    return __builtin_amdgcn_exp2f(x);
#else
    float r; asm("v_exp_f32 %0, %1" : "=v"(r) : "v"(x)); return r;
#endif
}

#if defined(__has_builtin)
#if __has_builtin(__builtin_amdgcn_global_load_lds)
#define HAS_GLDS 1
#endif
#endif

// async global->LDS, 16B per lane. LDS dest = wave-uniform base + lane*16.
__device__ __forceinline__ void gl_lds16(const unsigned short* g, unsigned short* lds_wave_base) {
#ifdef HAS_GLDS
    __builtin_amdgcn_global_load_lds(
        (const __attribute__((address_space(1))) void*)g,
        (__attribute__((address_space(3))) void*)lds_wave_base, 16, 0, 0);
#else
    int lane = threadIdx.x & 63;
    *(short8*)(lds_wave_base + lane * 8) = *(const short8*)g;
#endif
}

// ---------------- convert all f32 inputs to bf16 once ----------------
__global__ __launch_bounds__(256) void cvt_all(const float* __restrict__ q,
                                               const float* __restrict__ k,
                                               const float* __restrict__ v,
                                               const float* __restrict__ wq,
                                               const float* __restrict__ wk,
                                               const float* __restrict__ wv,
                                               const float* __restrict__ wo,
                                               unsigned short* __restrict__ xb,
                                               unsigned short* __restrict__ wb) {
    int bid = blockIdx.x;
    const float* src;
    unsigned short* dst;
    int chunk;
    if (bid < 12288) {
        int z = bid >> 12; chunk = bid & 4095;
        src = (z == 0) ? q : (z == 1) ? k : v;
        dst = xb + (size_t)z * ACT_ELEMS;
    } else {
        int z = (bid - 12288) >> 9; chunk = (bid - 12288) & 511;
        src = (z == 0) ? wq : (z == 1) ? wk : (z == 2) ? wv : wo;
        dst = wb + (size_t)z * W_ELEMS;
    }
    size_t i = (size_t)chunk * 2048 + (size_t)threadIdx.x * 8;
    f32x4 f0 = *(const f32x4*)(src + i);
    f32x4 f1 = *(const f32x4*)(src + i + 4);
    u32x2 p0 = {cvtpk_bf16(f0[0], f0[1]), cvtpk_bf16(f0[2], f0[3])};
    u32x2 p1 = {cvtpk_bf16(f1[0], f1[1]), cvtpk_bf16(f1[2], f1[3])};
    *(u32x2*)(dst + i) = p0;
    *(u32x2*)(dst + i + 4) = p1;
}

// ---------------- NT GEMM: C[m,n] = sum_k A[m,k]*W[n,k] + bias[n] ----------------
// K-loop unchanged (proven). STORE==0 epilogue: LDS-bounce to convert the
// (B,H,T,D)-permuted scatter (64 x 2B scalar stores/thread, 32B segments)
// into fully-coalesced dwordx4 runs (8 stores/thread, 1KB/wave-instr).
// Cs reuses the As/Bs pool after the K-loop's final barrier (no races:
// every wave passed that barrier before any Cs write).
template <int STORE>
__device__ __forceinline__ void gemm_body(const unsigned short* __restrict__ A,
                                          const unsigned short* __restrict__ W,
                                          const float* __restrict__ bias,
                                          unsigned short* __restrict__ dstb,
                                          float* __restrict__ dstf) {
    __shared__ unsigned short smem[17408];   // As[4096] Bs[4096] | Cs[128*136]
    unsigned short* As = smem;
    unsigned short* Bs = smem + 4096;
    unsigned short* Cs = smem;               // alias, live only after K-loop

    const int tid  = threadIdx.x;
    const int m0   = blockIdx.x * 128;
    const int n0   = blockIdx.y * 128;
    const int lane = tid & 63;
    const int wave = tid >> 6;
    const int col  = lane & 15;
    const int quad = lane >> 4;
    const int wr   = wave >> 1;
    const int wc   = wave & 1;

    f32x4 acc[4][4];
    const f32x4 fzero = {0.f, 0.f, 0.f, 0.f};
#pragma unroll
    for (int i = 0; i < 4; ++i)
#pragma unroll
        for (int j = 0; j < 4; ++j) acc[i][j] = fzero;

    for (int k0 = 0; k0 < NC; k0 += 32) {
#pragma unroll
        for (int r = 0; r < 2; ++r) {
            int g   = r * 256 + tid;
            int row = g >> 2;
            int cc  = (g & 3) * 8;
            unsigned short* abase = As + (size_t)(r * 2048 + wave * 512);
            unsigned short* bbase = Bs + (size_t)(r * 2048 + wave * 512);
            gl_lds16(A + (size_t)(m0 + row) * NC + k0 + cc, abase);
            gl_lds16(W + (size_t)(n0 + row) * NC + k0 + cc, bbase);
        }
        __syncthreads();

        short8 af[4], bf[4];
#pragma unroll
        for (int i = 0; i < 4; ++i)
            af[i] = *(const short8*)&As[(wr * 64 + i * 16 + col) * 32 + quad * 8];
#pragma unroll
        for (int j = 0; j < 4; ++j)
            bf[j] = *(const short8*)&Bs[(wc * 64 + j * 16 + col) * 32 + quad * 8];
#pragma unroll
        for (int i = 0; i < 4; ++i)
#pragma unroll
            for (int j = 0; j < 4; ++j)
                acc[i][j] = __builtin_amdgcn_mfma_f32_16x16x32_bf16(af[i], bf[j], acc[i][j], 0, 0, 0);
        __syncthreads();
    }

    // epilogue. C/D layout: col = lane&15, row = quad*4 + reg  [m89-verified]
    if (STORE == 0) {
        // pass 1: acc+bias -> Cs[ml][nl] bf16 (stride 136 shorts, 16B-aligned rows)
#pragma unroll
        for (int j = 0; j < 4; ++j) {
            int nl = wc * 64 + j * 16 + col;
            float bv = bias[n0 + nl];
#pragma unroll
            for (int i = 0; i < 4; ++i) {
#pragma unroll
                for (int r = 0; r < 4; ++r) {
                    int ml = wr * 64 + i * 16 + quad * 4 + r;
                    Cs[ml * 136 + nl] = f2bf(acc[i][j][r] + bv);
                }
            }
        }
        __syncthreads();
        // pass 2: coalesced store. 2048 chunks of 16B; chunk c -> row2=c>>3
        // (hl=row2>>7 head-local, ml=row2&127), d0=(c&7)*8. Consecutive tid ->
        // consecutive 16B -> contiguous 1KB per wave-instruction.
#pragma unroll
        for (int rr = 0; rr < 8; ++rr) {
            int c    = rr * 256 + tid;
            int row2 = c >> 3;
            int hl   = row2 >> 7;
            int ml   = row2 & 127;
            int d0   = (c & 7) * 8;
            short8 val = *(const short8*)&Cs[ml * 136 + hl * 64 + d0];
            int m = m0 + ml;
            int h = (n0 >> 6) + hl;
            size_t idx = ((size_t)((m >> 11) * NH + h) * NT + (m & 2047)) * ND + d0;
            *(short8*)(dstb + idx) = val;
        }
    } else {
#pragma unroll
        for (int j = 0; j < 4; ++j) {
            int n = n0 + wc * 64 + j * 16 + col;
            float bv = bias[n];
#pragma unroll
            for (int i = 0; i < 4; ++i) {
#pragma unroll
                for (int r = 0; r < 4; ++r) {
                    int m = m0 + wr * 64 + i * 16 + quad * 4 + r;
                    dstf[(size_t)m * NC + n] = acc[i][j][r] + bv;
                }
            }
        }
    }
}

__global__ __launch_bounds__(256) void proj_kernel(const unsigned short* __restrict__ xb,
                                                   const unsigned short* __restrict__ wb,
                                                   const float* __restrict__ b0,
                                                   const float* __restrict__ b1,
                                                   const float* __restrict__ b2,
                                                   unsigned short* __restrict__ qkv) {
    int z = blockIdx.z;
    const float* bias = (z == 0) ? b0 : (z == 1) ? b1 : b2;
    gemm_body<0>(xb + (size_t)z * ACT_ELEMS, wb + (size_t)z * W_ELEMS, bias,
                 qkv + (size_t)z * ACT_ELEMS, nullptr);
}

__global__ __launch_bounds__(256) void outproj_kernel(const unsigned short* __restrict__ ao,
                                                      const unsigned short* __restrict__ w,
                                                      const float* __restrict__ bias,
                                                      float* __restrict__ out) {
    gemm_body<1>(ao, w, bias, nullptr, out);
}

// ---------------- flash attention v12 (verified 413.9 us) ----------------
// Body = v9 (two barriers/iter, wave-specialized staging, T14 prefetch,
// softmax diet, T5 setprio) + XCD-chunked grid decode (kept: -10% FETCH,
// free ~4 us). FROZEN AXES (measured failures): K-direct (v7 5e-2),
// single-barrier dbuf (v8 6e-2), early-VMEM-issue (v11 6.7e-2),
// 16-row tiling (v10 FETCH 5x, attn 296 us).
__global__ __launch_bounds__(512, 4) void attn_kernel(const unsigned short* __restrict__ q,
                                                      const unsigned short* __restrict__ k,
                                                      const unsigned short* __restrict__ v,
                                                      const float* __restrict__ amask,
                                                      const unsigned char* __restrict__ kpm,
                                                      unsigned short* __restrict__ ao) {
    __shared__ unsigned short Ks[64 * 72];       // K  [s][d], padded (16B-aligned rows)
    __shared__ unsigned short Vt[64 * 72];       // V^T[d][s], padded
    __shared__ unsigned short Pl[8][32 * 72];    // per-wave P [t][s], padded

    const int tid  = threadIdx.x;
    const int lane = tid & 63;
    const int wave = tid >> 6;
    const int col  = lane & 15;
    const int quad = lane >> 4;

    // XCD-chunked decode: all 8 t-blocks of head-group gg share orig%8.
    const int orig = blockIdx.x;          // 0..511
    const int xcd  = orig & 7;
    const int w    = orig >> 3;           // 0..63
    const int gg   = xcd * 8 + (w >> 3);  // 0..63 head-group (b*16+h)
    const int tb   = w & 7;
    const int h    = gg & 15;
    const int b    = gg >> 4;
    const int t0   = tb * 256;

    const size_t headbase = (size_t)(b * NH + h) * NT * ND;

    const float LOG2E = 1.44269504089f;
    const float C1    = 0.125f * 1.44269504089f;   // scale * log2e

    // Q as B-operand frags: B[k=d][n=t], lane n=col, k=quad*8+j (+32)
    short8 qf[2][2];
#pragma unroll
    for (int tg = 0; tg < 2; ++tg) {
        const unsigned short* qr =
            q + headbase + (size_t)(t0 + wave * 32 + tg * 16 + col) * ND + quad * 8;
        qf[tg][0] = *(const short8*)qr;
        qf[tg][1] = *(const short8*)(qr + 32);
    }

    const f32x4 fzero = {0.f, 0.f, 0.f, 0.f};
    f32x4 O[2][4];
#pragma unroll
    for (int tg = 0; tg < 2; ++tg)
#pragma unroll
        for (int dg = 0; dg < 4; ++dg) O[tg][dg] = fzero;
    float lsum[2] = {0.f, 0.f};

    // staging roles: waves 0-3 stage V (transpose-pack), waves 4-7 stage K
    const bool isV = (wave < 4);
    const int g    = isV ? tid : (tid - 256);
    const int vsp  = g & 31;           // V s-pair 0..31
    const int vd0  = (g >> 5) * 8;     // V d chunk
    const int krow = g >> 2;           // K row 0..63
    const int kcs  = (g & 3) * 16;     // K col (shorts)

    unsigned short* Plw = Pl[wave];

    // amask row base for this lane's t-columns (t = t0 + wave*32 + tg*16 + col)
    const float* am0 = amask + (size_t)(t0 + wave * 32 + col) * NT;
    const float* am1 = am0 + 16 * NT;

    // ---- prologue: load tile s0=0 into regs ----
    short8 pre0, pre1;
    if (isV) {
        const unsigned short* vp = v + headbase + (size_t)(vsp * 2) * ND + vd0;
        pre0 = *(const short8*)vp;
        pre1 = *(const short8*)(vp + ND);
    } else {
        const unsigned short* kp_ = k + headbase + (size_t)krow * ND + kcs;
        pre0 = *(const short8*)kp_;
        pre1 = *(const short8*)(kp_ + 8);
    }

    for (int s0 = 0; s0 < NT; s0 += 64) {
        // ---- write staged tile (vmcnt wait on pre regs happens here) ----
        if (isV) {
            unsigned int* dst = (unsigned int*)Vt;
#pragma unroll
            for (int i = 0; i < 8; ++i) {
                unsigned int pk = (unsigned int)(unsigned short)pre0[i] |
                                  ((unsigned int)(unsigned short)pre1[i] << 16);
                dst[(vd0 + i) * 36 + vsp] = pk;
            }
        } else {
            *(short8*)&Ks[krow * 72 + kcs]     = pre0;
            *(short8*)&Ks[krow * 72 + kcs + 8] = pre1;
        }

        // ---- hoisted mask loads: issue before barrier, consumed after QK ----
        unsigned int kbv[4];
        f32x4 mvv[4][2];
#pragma unroll
        for (int sg = 0; sg < 4; ++sg) {
            int sc = s0 + sg * 16 + quad * 4;
            kbv[sg]    = *(const unsigned int*)(kpm + b * NT + sc);
            mvv[sg][0] = *(const f32x4*)(am0 + sc);
            mvv[sg][1] = *(const f32x4*)(am1 + sc);
        }
        __syncthreads();

        // ---- S^T = K Q^T : C[row=s-local=quad*4+r][col=t-local16] ----
#pragma unroll
        for (int sg = 0; sg < 4; ++sg) {
            const unsigned short* kb_ = &Ks[(sg * 16 + col) * 72 + quad * 8];
            short8 af0 = *(const short8*)kb_;
            short8 af1 = *(const short8*)(kb_ + 32);
            float km[4];   // per-(sg,r) additive mask: 0 or -inf
#pragma unroll
            for (int r = 0; r < 4; ++r)
                km[r] = ((kbv[sg] >> (r * 8)) & 0xffu) ? -INFINITY : 0.0f;
#pragma unroll
            for (int tg = 0; tg < 2; ++tg) {
                f32x4 z = fzero;
                __builtin_amdgcn_s_setprio(1);
                z = __builtin_amdgcn_mfma_f32_16x16x32_bf16(af0, qf[tg][0], z, 0, 0, 0);
                z = __builtin_amdgcn_mfma_f32_16x16x32_bf16(af1, qf[tg][1], z, 0, 0, 0);
                __builtin_amdgcn_s_setprio(0);
                float p[4];
#pragma unroll
                for (int r = 0; r < 4; ++r) {
                    float t1 = __builtin_fmaf(mvv[sg][tg][r], LOG2E, km[r]);
                    p[r] = fexp2(__builtin_fmaf(z[r], C1, t1));
                }
                lsum[tg] += (p[0] + p[1]) + (p[2] + p[3]);
                u32x2 pkv;
                pkv[0] = cvtpk_bf16(p[0], p[1]);
                pkv[1] = cvtpk_bf16(p[2], p[3]);
                *(u32x2*)&Plw[(tg * 16 + col) * 72 + sg * 16 + quad * 4] = pkv;
            }
        }

        // ---- T14: issue next tile's global loads (complete under PV) ----
        {
            int sn = (s0 + 64 < NT) ? (s0 + 64) : 0;
            if (isV) {
                const unsigned short* vp = v + headbase + (size_t)(sn + vsp * 2) * ND + vd0;
                pre0 = *(const short8*)vp;
                pre1 = *(const short8*)(vp + ND);
            } else {
                const unsigned short* kp_ = k + headbase + (size_t)(sn + krow) * ND + kcs;
                pre0 = *(const short8*)kp_;
                pre1 = *(const short8*)(kp_ + 8);
            }
        }

        // ---- O += P V  (A=P[t][s] b128, B=V^T rows) ----
        short8 pf[2][2];
#pragma unroll
        for (int tg = 0; tg < 2; ++tg)
#pragma unroll
            for (int sk = 0; sk < 2; ++sk)
                pf[tg][sk] = *(const short8*)&Plw[(tg * 16 + col) * 72 + sk * 32 + quad * 8];
#pragma unroll
        for (int dg = 0; dg < 4; ++dg) {
            short8 vf0 = *(const short8*)&Vt[(dg * 16 + col) * 72 + quad * 8];
            short8 vf1 = *(const short8*)&Vt[(dg * 16 + col) * 72 + 32 + quad * 8];
            __builtin_amdgcn_s_setprio(1);
#pragma unroll
            for (int tg = 0; tg < 2; ++tg) {
                O[tg][dg] = __builtin_amdgcn_mfma_f32_16x16x32_bf16(pf[tg][0], vf0, O[tg][dg], 0, 0, 0);
                O[tg][dg] = __builtin_amdgcn_mfma_f32_16x16x32_bf16(pf[tg][1], vf1, O[tg][dg], 0, 0, 0);
            }
            __builtin_amdgcn_s_setprio(0);
        }
        __syncthreads();
    }

    // ---- l reduction (once) + epilogue ----
    float linv[2];
#pragma unroll
    for (int tg = 0; tg < 2; ++tg) {
        float s = lsum[tg];
        s += __shfl_xor(s, 16);
        s += __shfl_xor(s, 32);
        linv[tg] = 1.0f / s;
    }
#pragma unroll
    for (int tg = 0; tg < 2; ++tg) {
#pragma unroll
        for (int r = 0; r < 4; ++r) {
            float inv = __shfl(linv[tg], quad * 4 + r);
            int t = t0 + wave * 32 + tg * 16 + quad * 4 + r;
#pragma unroll
            for (int dg = 0; dg < 4; ++dg) {
                size_t idx = (size_t)(b * NT + t) * NC + h * ND + dg * 16 + col;
                ao[idx] = f2bf(O[tg][dg][r] * inv);
            }
        }
    }
}

// ---------------- launch ----------------
extern "C" void kernel_launch(void* const* d_in, const int* in_sizes, int n_in,
                              void* d_out, int out_size, void* d_ws, size_t ws_size,
                              hipStream_t stream) {
    const float* query = (const float*)d_in[0];
    const float* key_  = (const float*)d_in[1];
    const float* value = (const float*)d_in[2];
    const float* amask = (const float*)d_in[3];
    const unsigned char* kpm = (const unsigned char*)d_in[4];
    const float* Wq = (const float*)d_in[5];
    const float* bq = (const float*)d_in[6];
    const float* Wk = (const float*)d_in[7];
    const float* bk = (const float*)d_in[8];
    const float* Wv = (const float*)d_in[9];
    const float* bv = (const float*)d_in[10];
    const float* Wo = (const float*)d_in[11];
    const float* bo = (const float*)d_in[12];
    float* out = (float*)d_out;

    unsigned short* ws = (unsigned short*)d_ws;
    unsigned short* xb  = ws;                   // bf16 acts (query,key,value), 24M shorts
    unsigned short* qb  = ws + 3 * ACT_ELEMS;   // q,k,v projected (B,H,T,D), 24M shorts
    unsigned short* wb  = ws + 6 * ACT_ELEMS;   // 4 weights bf16, 4M shorts
    unsigned short* aob = xb;                   // attn_out aliases dead xb[0..8M)

    cvt_all<<<14336, 256, 0, stream>>>(query, key_, value, Wq, Wk, Wv, Wo, xb, wb);

    dim3 pg(64, 8, 3);
    proj_kernel<<<pg, 256, 0, stream>>>(xb, wb, bq, bk, bv, qb);

    attn_kernel<<<512, 512, 0, stream>>>(qb, qb + ACT_ELEMS, qb + 2 * ACT_ELEMS,
                                         amask, kpm, aob);

    dim3 og(64, 8, 1);
    outproj_kernel<<<og, 256, 0, stream>>>(aob, wb + 3 * W_ELEMS, bo, out);
}

// Round 13
// 412.745 us; speedup vs baseline: 1.0037x; 1.0037x over previous
//
#include <hip/hip_runtime.h>
#include <stdint.h>

// ---- problem dims (fixed) ----
// B=4, T=S=2048, C=1024, H=16, D=64
#define NB 4
#define NT 2048
#define NC 1024
#define NH 16
#define ND 64
#define ACT_ELEMS (8388608ull)   /* B*T*C = 8M */
#define W_ELEMS   (1048576ull)   /* C*C = 1M  */

typedef __attribute__((ext_vector_type(8))) short short8;
typedef __attribute__((ext_vector_type(4))) float f32x4;
typedef __attribute__((ext_vector_type(2))) unsigned int u32x2;

__device__ __forceinline__ unsigned short f2bf(float x) {
    unsigned int u = __float_as_uint(x);
    u += 0x7fffu + ((u >> 16) & 1u);   // RNE
    return (unsigned short)(u >> 16);
}

// hardware packed f32->bf16 (RNE), 1 VALU op for 2 values [T12 primitive]
__device__ __forceinline__ unsigned int cvtpk_bf16(float a, float b) {
    unsigned int r;
    asm("v_cvt_pk_bf16_f32 %0, %1, %2" : "=v"(r) : "v"(a), "v"(b));
    return r;
}

__device__ __forceinline__ float fexp2(float x) {
#if defined(__has_builtin) && __has_builtin(__builtin_amdgcn_exp2f)
    return __builtin_amdgcn_exp2f(x);
#else
    float r; asm("v_exp_f32 %0, %1" : "=v"(r) : "v"(x)); return r;
#endif
}

#if defined(__has_builtin)
#if __has_builtin(__builtin_amdgcn_global_load_lds)
#define HAS_GLDS 1
#endif
#endif

// async global->LDS, 16B per lane. LDS dest = wave-uniform base + lane*16.
__device__ __forceinline__ void gl_lds16(const unsigned short* g, unsigned short* lds_wave_base) {
#ifdef HAS_GLDS
    __builtin_amdgcn_global_load_lds(
        (const __attribute__((address_space(1))) void*)g,
        (__attribute__((address_space(3))) void*)lds_wave_base, 16, 0, 0);
#else
    int lane = threadIdx.x & 63;
    *(short8*)(lds_wave_base + lane * 8) = *(const short8*)g;
#endif
}

// ---------------- convert all f32 inputs to bf16 once ----------------
__global__ __launch_bounds__(256) void cvt_all(const float* __restrict__ q,
                                               const float* __restrict__ k,
                                               const float* __restrict__ v,
                                               const float* __restrict__ wq,
                                               const float* __restrict__ wk,
                                               const float* __restrict__ wv,
                                               const float* __restrict__ wo,
                                               unsigned short* __restrict__ xb,
                                               unsigned short* __restrict__ wb) {
    int bid = blockIdx.x;
    const float* src;
    unsigned short* dst;
    int chunk;
    if (bid < 12288) {
        int z = bid >> 12; chunk = bid & 4095;
        src = (z == 0) ? q : (z == 1) ? k : v;
        dst = xb + (size_t)z * ACT_ELEMS;
    } else {
        int z = (bid - 12288) >> 9; chunk = (bid - 12288) & 511;
        src = (z == 0) ? wq : (z == 1) ? wk : (z == 2) ? wv : wo;
        dst = wb + (size_t)z * W_ELEMS;
    }
    size_t i = (size_t)chunk * 2048 + (size_t)threadIdx.x * 8;
    f32x4 f0 = *(const f32x4*)(src + i);
    f32x4 f1 = *(const f32x4*)(src + i + 4);
    u32x2 p0 = {cvtpk_bf16(f0[0], f0[1]), cvtpk_bf16(f0[2], f0[3])};
    u32x2 p1 = {cvtpk_bf16(f1[0], f1[1]), cvtpk_bf16(f1[2], f1[3])};
    *(u32x2*)(dst + i) = p0;
    *(u32x2*)(dst + i + 4) = p1;
}

// ---------------- NT GEMM: C[m,n] = sum_k A[m,k]*W[n,k] + bias[n] ----------------
// v14: BK=64 — two independent 32-wide sub-tiles staged per barrier pair
// (As[2]/Bs[2], each the proven [128][32] layout, same gl_lds16 pattern,
// same fragment reads). Halves barrier count (32 -> 16 per K-loop).
// Accumulation order unchanged (k0 then k0+32) -> bit-identical output.
// LDS 32 KB; blocks/CU stays VGPR-bound at 3 (m132's BK=128 regression was
// the 64KB-LDS occupancy cliff, avoided here).
template <int STORE>
__device__ __forceinline__ void gemm_body(const unsigned short* __restrict__ A,
                                          const unsigned short* __restrict__ W,
                                          const float* __restrict__ bias,
                                          unsigned short* __restrict__ dstb,
                                          float* __restrict__ dstf) {
    __shared__ unsigned short smem[17408];   // 34,816 B: 4x4096 staging | Cs[128*136]
    unsigned short* Ts[4] = {smem, smem + 4096, smem + 8192, smem + 12288};
    unsigned short* Cs = smem;               // alias, live only after K-loop

    const int tid  = threadIdx.x;
    const int m0   = blockIdx.x * 128;
    const int n0   = blockIdx.y * 128;
    const int lane = tid & 63;
    const int wave = tid >> 6;
    const int col  = lane & 15;
    const int quad = lane >> 4;
    const int wr   = wave >> 1;
    const int wc   = wave & 1;

    f32x4 acc[4][4];
    const f32x4 fzero = {0.f, 0.f, 0.f, 0.f};
#pragma unroll
    for (int i = 0; i < 4; ++i)
#pragma unroll
        for (int j = 0; j < 4; ++j) acc[i][j] = fzero;

    for (int k0 = 0; k0 < NC; k0 += 64) {
        // stage both 32-wide sub-tiles of A and W (16 gl_lds16 per thread-pass)
#pragma unroll
        for (int half = 0; half < 2; ++half) {
#pragma unroll
            for (int r = 0; r < 2; ++r) {
                int g   = r * 256 + tid;
                int row = g >> 2;
                int cc  = (g & 3) * 8;
                unsigned short* abase = Ts[half]     + (size_t)(r * 2048 + wave * 512);
                unsigned short* bbase = Ts[2 + half] + (size_t)(r * 2048 + wave * 512);
                gl_lds16(A + (size_t)(m0 + row) * NC + k0 + half * 32 + cc, abase);
                gl_lds16(W + (size_t)(n0 + row) * NC + k0 + half * 32 + cc, bbase);
            }
        }
        __syncthreads();

#pragma unroll
        for (int half = 0; half < 2; ++half) {
            const unsigned short* As_ = Ts[half];
            const unsigned short* Bs_ = Ts[2 + half];
            short8 af[4], bf[4];
#pragma unroll
            for (int i = 0; i < 4; ++i)
                af[i] = *(const short8*)&As_[(wr * 64 + i * 16 + col) * 32 + quad * 8];
#pragma unroll
            for (int j = 0; j < 4; ++j)
                bf[j] = *(const short8*)&Bs_[(wc * 64 + j * 16 + col) * 32 + quad * 8];
#pragma unroll
            for (int i = 0; i < 4; ++i)
#pragma unroll
                for (int j = 0; j < 4; ++j)
                    acc[i][j] = __builtin_amdgcn_mfma_f32_16x16x32_bf16(af[i], bf[j], acc[i][j], 0, 0, 0);
        }
        __syncthreads();
    }

    // epilogue. C/D layout: col = lane&15, row = quad*4 + reg  [m89-verified]
    if (STORE == 0) {
        // pass 1: acc+bias -> Cs[ml][nl] bf16 (stride 136 shorts, 16B-aligned rows)
#pragma unroll
        for (int j = 0; j < 4; ++j) {
            int nl = wc * 64 + j * 16 + col;
            float bv = bias[n0 + nl];
#pragma unroll
            for (int i = 0; i < 4; ++i) {
#pragma unroll
                for (int r = 0; r < 4; ++r) {
                    int ml = wr * 64 + i * 16 + quad * 4 + r;
                    Cs[ml * 136 + nl] = f2bf(acc[i][j][r] + bv);
                }
            }
        }
        __syncthreads();
        // pass 2: coalesced store. 2048 chunks of 16B; chunk c -> row2=c>>3
        // (hl=row2>>7 head-local, ml=row2&127), d0=(c&7)*8.
#pragma unroll
        for (int rr = 0; rr < 8; ++rr) {
            int c    = rr * 256 + tid;
            int row2 = c >> 3;
            int hl   = row2 >> 7;
            int ml   = row2 & 127;
            int d0   = (c & 7) * 8;
            short8 val = *(const short8*)&Cs[ml * 136 + hl * 64 + d0];
            int m = m0 + ml;
            int h = (n0 >> 6) + hl;
            size_t idx = ((size_t)((m >> 11) * NH + h) * NT + (m & 2047)) * ND + d0;
            *(short8*)(dstb + idx) = val;
        }
    } else {
#pragma unroll
        for (int j = 0; j < 4; ++j) {
            int n = n0 + wc * 64 + j * 16 + col;
            float bv = bias[n];
#pragma unroll
            for (int i = 0; i < 4; ++i) {
#pragma unroll
                for (int r = 0; r < 4; ++r) {
                    int m = m0 + wr * 64 + i * 16 + quad * 4 + r;
                    dstf[(size_t)m * NC + n] = acc[i][j][r] + bv;
                }
            }
        }
    }
}

__global__ __launch_bounds__(256) void proj_kernel(const unsigned short* __restrict__ xb,
                                                   const unsigned short* __restrict__ wb,
                                                   const float* __restrict__ b0,
                                                   const float* __restrict__ b1,
                                                   const float* __restrict__ b2,
                                                   unsigned short* __restrict__ qkv) {
    int z = blockIdx.z;
    const float* bias = (z == 0) ? b0 : (z == 1) ? b1 : b2;
    gemm_body<0>(xb + (size_t)z * ACT_ELEMS, wb + (size_t)z * W_ELEMS, bias,
                 qkv + (size_t)z * ACT_ELEMS, nullptr);
}

__global__ __launch_bounds__(256) void outproj_kernel(const unsigned short* __restrict__ ao,
                                                      const unsigned short* __restrict__ w,
                                                      const float* __restrict__ bias,
                                                      float* __restrict__ out) {
    gemm_body<1>(ao, w, bias, nullptr, out);
}

// ---------------- flash attention v12 (verified 413.9 us) ----------------
// Body = v9 (two barriers/iter, wave-specialized staging, T14 prefetch,
// softmax diet, T5 setprio) + XCD-chunked grid decode. BYTE-IDENTICAL to
// the round-11 verified kernel. FROZEN AXES (measured failures): K-direct
// (v7 5e-2), single-barrier dbuf (v8 6e-2), early-VMEM-issue (v11 6.7e-2),
// 16-row tiling (v10 FETCH 5x, attn 296 us).
__global__ __launch_bounds__(512, 4) void attn_kernel(const unsigned short* __restrict__ q,
                                                      const unsigned short* __restrict__ k,
                                                      const unsigned short* __restrict__ v,
                                                      const float* __restrict__ amask,
                                                      const unsigned char* __restrict__ kpm,
                                                      unsigned short* __restrict__ ao) {
    __shared__ unsigned short Ks[64 * 72];       // K  [s][d], padded (16B-aligned rows)
    __shared__ unsigned short Vt[64 * 72];       // V^T[d][s], padded
    __shared__ unsigned short Pl[8][32 * 72];    // per-wave P [t][s], padded

    const int tid  = threadIdx.x;
    const int lane = tid & 63;
    const int wave = tid >> 6;
    const int col  = lane & 15;
    const int quad = lane >> 4;

    // XCD-chunked decode: all 8 t-blocks of head-group gg share orig%8.
    const int orig = blockIdx.x;          // 0..511
    const int xcd  = orig & 7;
    const int w    = orig >> 3;           // 0..63
    const int gg   = xcd * 8 + (w >> 3);  // 0..63 head-group (b*16+h)
    const int tb   = w & 7;
    const int h    = gg & 15;
    const int b    = gg >> 4;
    const int t0   = tb * 256;

    const size_t headbase = (size_t)(b * NH + h) * NT * ND;

    const float LOG2E = 1.44269504089f;
    const float C1    = 0.125f * 1.44269504089f;   // scale * log2e

    // Q as B-operand frags: B[k=d][n=t], lane n=col, k=quad*8+j (+32)
    short8 qf[2][2];
#pragma unroll
    for (int tg = 0; tg < 2; ++tg) {
        const unsigned short* qr =
            q + headbase + (size_t)(t0 + wave * 32 + tg * 16 + col) * ND + quad * 8;
        qf[tg][0] = *(const short8*)qr;
        qf[tg][1] = *(const short8*)(qr + 32);
    }

    const f32x4 fzero = {0.f, 0.f, 0.f, 0.f};
    f32x4 O[2][4];
#pragma unroll
    for (int tg = 0; tg < 2; ++tg)
#pragma unroll
        for (int dg = 0; dg < 4; ++dg) O[tg][dg] = fzero;
    float lsum[2] = {0.f, 0.f};

    // staging roles: waves 0-3 stage V (transpose-pack), waves 4-7 stage K
    const bool isV = (wave < 4);
    const int g    = isV ? tid : (tid - 256);
    const int vsp  = g & 31;           // V s-pair 0..31
    const int vd0  = (g >> 5) * 8;     // V d chunk
    const int krow = g >> 2;           // K row 0..63
    const int kcs  = (g & 3) * 16;     // K col (shorts)

    unsigned short* Plw = Pl[wave];

    // amask row base for this lane's t-columns (t = t0 + wave*32 + tg*16 + col)
    const float* am0 = amask + (size_t)(t0 + wave * 32 + col) * NT;
    const float* am1 = am0 + 16 * NT;

    // ---- prologue: load tile s0=0 into regs ----
    short8 pre0, pre1;
    if (isV) {
        const unsigned short* vp = v + headbase + (size_t)(vsp * 2) * ND + vd0;
        pre0 = *(const short8*)vp;
        pre1 = *(const short8*)(vp + ND);
    } else {
        const unsigned short* kp_ = k + headbase + (size_t)krow * ND + kcs;
        pre0 = *(const short8*)kp_;
        pre1 = *(const short8*)(kp_ + 8);
    }

    for (int s0 = 0; s0 < NT; s0 += 64) {
        // ---- write staged tile (vmcnt wait on pre regs happens here) ----
        if (isV) {
            unsigned int* dst = (unsigned int*)Vt;
#pragma unroll
            for (int i = 0; i < 8; ++i) {
                unsigned int pk = (unsigned int)(unsigned short)pre0[i] |
                                  ((unsigned int)(unsigned short)pre1[i] << 16);
                dst[(vd0 + i) * 36 + vsp] = pk;
            }
        } else {
            *(short8*)&Ks[krow * 72 + kcs]     = pre0;
            *(short8*)&Ks[krow * 72 + kcs + 8] = pre1;
        }

        // ---- hoisted mask loads: issue before barrier, consumed after QK ----
        unsigned int kbv[4];
        f32x4 mvv[4][2];
#pragma unroll
        for (int sg = 0; sg < 4; ++sg) {
            int sc = s0 + sg * 16 + quad * 4;
            kbv[sg]    = *(const unsigned int*)(kpm + b * NT + sc);
            mvv[sg][0] = *(const f32x4*)(am0 + sc);
            mvv[sg][1] = *(const f32x4*)(am1 + sc);
        }
        __syncthreads();

        // ---- S^T = K Q^T : C[row=s-local=quad*4+r][col=t-local16] ----
#pragma unroll
        for (int sg = 0; sg < 4; ++sg) {
            const unsigned short* kb_ = &Ks[(sg * 16 + col) * 72 + quad * 8];
            short8 af0 = *(const short8*)kb_;
            short8 af1 = *(const short8*)(kb_ + 32);
            float km[4];   // per-(sg,r) additive mask: 0 or -inf
#pragma unroll
            for (int r = 0; r < 4; ++r)
                km[r] = ((kbv[sg] >> (r * 8)) & 0xffu) ? -INFINITY : 0.0f;
#pragma unroll
            for (int tg = 0; tg < 2; ++tg) {
                f32x4 z = fzero;
                __builtin_amdgcn_s_setprio(1);
                z = __builtin_amdgcn_mfma_f32_16x16x32_bf16(af0, qf[tg][0], z, 0, 0, 0);
                z = __builtin_amdgcn_mfma_f32_16x16x32_bf16(af1, qf[tg][1], z, 0, 0, 0);
                __builtin_amdgcn_s_setprio(0);
                float p[4];
#pragma unroll
                for (int r = 0; r < 4; ++r) {
                    float t1 = __builtin_fmaf(mvv[sg][tg][r], LOG2E, km[r]);
                    p[r] = fexp2(__builtin_fmaf(z[r], C1, t1));
                }
                lsum[tg] += (p[0] + p[1]) + (p[2] + p[3]);
                u32x2 pkv;
                pkv[0] = cvtpk_bf16(p[0], p[1]);
                pkv[1] = cvtpk_bf16(p[2], p[3]);
                *(u32x2*)&Plw[(tg * 16 + col) * 72 + sg * 16 + quad * 4] = pkv;
            }
        }

        // ---- T14: issue next tile's global loads (complete under PV) ----
        {
            int sn = (s0 + 64 < NT) ? (s0 + 64) : 0;
            if (isV) {
                const unsigned short* vp = v + headbase + (size_t)(sn + vsp * 2) * ND + vd0;
                pre0 = *(const short8*)vp;
                pre1 = *(const short8*)(vp + ND);
            } else {
                const unsigned short* kp_ = k + headbase + (size_t)(sn + krow) * ND + kcs;
                pre0 = *(const short8*)kp_;
                pre1 = *(const short8*)(kp_ + 8);
            }
        }

        // ---- O += P V  (A=P[t][s] b128, B=V^T rows) ----
        short8 pf[2][2];
#pragma unroll
        for (int tg = 0; tg < 2; ++tg)
#pragma unroll
            for (int sk = 0; sk < 2; ++sk)
                pf[tg][sk] = *(const short8*)&Plw[(tg * 16 + col) * 72 + sk * 32 + quad * 8];
#pragma unroll
        for (int dg = 0; dg < 4; ++dg) {
            short8 vf0 = *(const short8*)&Vt[(dg * 16 + col) * 72 + quad * 8];
            short8 vf1 = *(const short8*)&Vt[(dg * 16 + col) * 72 + 32 + quad * 8];
            __builtin_amdgcn_s_setprio(1);
#pragma unroll
            for (int tg = 0; tg < 2; ++tg) {
                O[tg][dg] = __builtin_amdgcn_mfma_f32_16x16x32_bf16(pf[tg][0], vf0, O[tg][dg], 0, 0, 0);
                O[tg][dg] = __builtin_amdgcn_mfma_f32_16x16x32_bf16(pf[tg][1], vf1, O[tg][dg], 0, 0, 0);
            }
            __builtin_amdgcn_s_setprio(0);
        }
        __syncthreads();
    }

    // ---- l reduction (once) + epilogue ----
    float linv[2];
#pragma unroll
    for (int tg = 0; tg < 2; ++tg) {
        float s = lsum[tg];
        s += __shfl_xor(s, 16);
        s += __shfl_xor(s, 32);
        linv[tg] = 1.0f / s;
    }
#pragma unroll
    for (int tg = 0; tg < 2; ++tg) {
#pragma unroll
        for (int r = 0; r < 4; ++r) {
            float inv = __shfl(linv[tg], quad * 4 + r);
            int t = t0 + wave * 32 + tg * 16 + quad * 4 + r;
#pragma unroll
            for (int dg = 0; dg < 4; ++dg) {
                size_t idx = (size_t)(b * NT + t) * NC + h * ND + dg * 16 + col;
                ao[idx] = f2bf(O[tg][dg][r] * inv);
            }
        }
    }
}

// ---------------- launch ----------------
extern "C" void kernel_launch(void* const* d_in, const int* in_sizes, int n_in,
                              void* d_out, int out_size, void* d_ws, size_t ws_size,
                              hipStream_t stream) {
    const float* query = (const float*)d_in[0];
    const float* key_  = (const float*)d_in[1];
    const float* value = (const float*)d_in[2];
    const float* amask = (const float*)d_in[3];
    const unsigned char* kpm = (const unsigned char*)d_in[4];
    const float* Wq = (const float*)d_in[5];
    const float* bq = (const float*)d_in[6];
    const float* Wk = (const float*)d_in[7];
    const float* bk = (const float*)d_in[8];
    const float* Wv = (const float*)d_in[9];
    const float* bv = (const float*)d_in[10];
    const float* Wo = (const float*)d_in[11];
    const float* bo = (const float*)d_in[12];
    float* out = (float*)d_out;

    unsigned short* ws = (unsigned short*)d_ws;
    unsigned short* xb  = ws;                   // bf16 acts (query,key,value), 24M shorts
    unsigned short* qb  = ws + 3 * ACT_ELEMS;   // q,k,v projected (B,H,T,D), 24M shorts
    unsigned short* wb  = ws + 6 * ACT_ELEMS;   // 4 weights bf16, 4M shorts
    unsigned short* aob = xb;                   // attn_out aliases dead xb[0..8M)

    cvt_all<<<14336, 256, 0, stream>>>(query, key_, value, Wq, Wk, Wv, Wo, xb, wb);

    dim3 pg(64, 8, 3);
    proj_kernel<<<pg, 256, 0, stream>>>(xb, wb, bq, bk, bv, qb);

    attn_kernel<<<512, 512, 0, stream>>>(qb, qb + ACT_ELEMS, qb + 2 * ACT_ELEMS,
                                         amask, kpm, aob);

    dim3 og(64, 8, 1);
    outproj_kernel<<<og, 256, 0, stream>>>(aob, wb + 3 * W_ELEMS, bo, out);
}